// Round 15
// baseline (207.293 us; speedup 1.0000x reference)
//
#include <hip/hip_runtime.h>
#include <math.h>

#define NB 4
#define NS 2048
#define DMODEL 1024
#define DSPACE 64
#define NPOOL 512
#define NHEADS 6
#define NTOK (NB * NS)            // 8192
#define PROJN (NHEADS * DSPACE)   // 384
#define EPSF 1e-8f

typedef float f32x2 __attribute__((ext_vector_type(2)));
typedef float f32x4 __attribute__((ext_vector_type(4)));

// packed f32 FMA: both halves multiply by S1.lo / S1.hi (broadcast via op_sel)
#define PK_LO(ACC, A2, B2) \
    asm("v_pk_fma_f32 %0, %1, %2, %0 op_sel:[0,0,0] op_sel_hi:[1,0,1]" \
        : "+v"(ACC) : "v"(A2), "v"(B2))
#define PK_HI(ACC, A2, B2) \
    asm("v_pk_fma_f32 %0, %1, %2, %0 op_sel:[0,1,0] op_sel_hi:[1,1,1]" \
        : "+v"(ACC) : "v"(A2), "v"(B2))

#define LO2(V4) __builtin_shufflevector(V4, V4, 0, 1)
#define HI2(V4) __builtin_shufflevector(V4, V4, 2, 3)

// ---------------- K1: normalize neuron_emb rows [0,2048) -> embT[64][2048]
__global__ __launch_bounds__(256) void k_norm_emb(const float* __restrict__ emb,
                                                  float* __restrict__ embT) {
    int row  = blockIdx.x * 4 + (threadIdx.x >> 6);
    int lane = threadIdx.x & 63;
    float v  = emb[row * DSPACE + lane];
    float ss = v * v;
#pragma unroll
    for (int off = 32; off >= 1; off >>= 1) ss += __shfl_xor(ss, off, 64);
    float nrm = sqrtf(ss) + EPSF;
    embT[lane * 2048 + row] = v / nrm;
}

// ---------------- K2: proj = X @ W + b, split-K partials — ALL-VMEM GEMM
// DS model (m134): ds_read_b128=12cyc on the per-CU DS pipe made the R8 LDS
// version DS-issue-bound at exactly 71us. Here every thread's 8 rows / 8 cols
// are exclusively its own -> no broadcast needed -> operands straight from
// global via L1/L2 (dup-lane addrs coalesce; each 64B line serves 4 k-groups).
// Per 4k-group: 16 VMEM (~4cyc issue) feeds 128 pk-FMA -> VALU-bound (~41us
// floor). Zero LDS, zero barriers. Same k-ascending order -> bitwise-same out.
__global__ __launch_bounds__(128, 3) void k_proj(const float* __restrict__ X,
                                                 const float* __restrict__ W,
                                                 const float* __restrict__ bias,
                                                 float* __restrict__ P, int KS) {
    const int tid = threadIdx.x;
    const int bm  = blockIdx.x * 128;
    const int bn  = blockIdx.y * 64;
    const int z   = blockIdx.z;
    float* Pp = P + (size_t)z * NTOK * PROJN;

    const int r0 = (tid >> 3) << 2;   // rows r0..r0+3 and r0+64..r0+67
    const int c0 = (tid & 7) << 2;    // cols c0..c0+3 and c0+32..c0+35

    const float* X0 = X + (size_t)(bm + r0) * DMODEL;        // rows r0+i
    const float* X4 = X + (size_t)(bm + r0 + 64) * DMODEL;   // rows r0+64+i

    // acc2[i][jp]: row i (0..3 -> r0+i, 4..7 -> r0+64+i-4); col-pair jp:
    // 0,1 -> cols c0+{0,1},{2,3}; 2,3 -> cols c0+32+{0,1},{2,3}
    f32x2 acc2[8][4];
#pragma unroll
    for (int i = 0; i < 8; ++i)
#pragma unroll
        for (int jp = 0; jp < 4; ++jp) acc2[i][jp] = (f32x2){0.f, 0.f};

    const int k0 = z * KS;
    for (int g = 0; g < KS; g += 4) {
        const int kb = k0 + g;
        f32x4 xr[8];
#pragma unroll
        for (int i = 0; i < 4; ++i) {
            xr[i]     = *(const f32x4*)&X0[(size_t)i * DMODEL + kb];
            xr[i + 4] = *(const f32x4*)&X4[(size_t)i * DMODEL + kb];
        }
        f32x4 wq[4][2];
#pragma unroll
        for (int q = 0; q < 4; ++q) {
            const float* wrow = &W[(size_t)(kb + q) * PROJN + bn];
            wq[q][0] = *(const f32x4*)&wrow[c0];
            wq[q][1] = *(const f32x4*)&wrow[c0 + 32];
        }
#pragma unroll
        for (int i = 0; i < 8; ++i) {
            f32x2 xlo = LO2(xr[i]);   // (k0, k1)
            f32x2 xhi = HI2(xr[i]);   // (k2, k3)
            // k = kb+0  (xlo.lo)
            PK_LO(acc2[i][0], LO2(wq[0][0]), xlo);
            PK_LO(acc2[i][1], HI2(wq[0][0]), xlo);
            PK_LO(acc2[i][2], LO2(wq[0][1]), xlo);
            PK_LO(acc2[i][3], HI2(wq[0][1]), xlo);
            // k = kb+1  (xlo.hi)
            PK_HI(acc2[i][0], LO2(wq[1][0]), xlo);
            PK_HI(acc2[i][1], HI2(wq[1][0]), xlo);
            PK_HI(acc2[i][2], LO2(wq[1][1]), xlo);
            PK_HI(acc2[i][3], HI2(wq[1][1]), xlo);
            // k = kb+2  (xhi.lo)
            PK_LO(acc2[i][0], LO2(wq[2][0]), xhi);
            PK_LO(acc2[i][1], HI2(wq[2][0]), xhi);
            PK_LO(acc2[i][2], LO2(wq[2][1]), xhi);
            PK_LO(acc2[i][3], HI2(wq[2][1]), xhi);
            // k = kb+3  (xhi.hi)
            PK_HI(acc2[i][0], LO2(wq[3][0]), xhi);
            PK_HI(acc2[i][1], HI2(wq[3][0]), xhi);
            PK_HI(acc2[i][2], LO2(wq[3][1]), xhi);
            PK_HI(acc2[i][3], HI2(wq[3][1]), xhi);
        }
    }

    // epilogue: rows {r0+i (i<4), r0+64+(i-4)}; bias on slab 0
#pragma unroll
    for (int i = 0; i < 8; ++i) {
        int row = bm + r0 + ((i < 4) ? i : 60 + i);
        float o0[4], o1[4];
        o0[0] = acc2[i][0].x; o0[1] = acc2[i][0].y;
        o0[2] = acc2[i][1].x; o0[3] = acc2[i][1].y;
        o1[0] = acc2[i][2].x; o1[1] = acc2[i][2].y;
        o1[2] = acc2[i][3].x; o1[3] = acc2[i][3].y;
        if (z == 0) {
#pragma unroll
            for (int j = 0; j < 4; ++j) {
                o0[j] += bias[bn + c0 + j];
                o1[j] += bias[bn + c0 + 32 + j];
            }
        }
        *(float4*)&Pp[(size_t)row * PROJN + bn + c0]      = *(float4*)&o0[0];
        *(float4*)&Pp[(size_t)row * PROJN + bn + c0 + 32] = *(float4*)&o1[0];
    }
}

// compare-exchange keeping larger value at index a (descending order)
#define CE(arr, a, b) { float _hi = fmaxf(arr[a], arr[b]); arr[b] = fminf(arr[a], arr[b]); arr[a] = _hi; }

#define SORT8(s) \
    CE(s,0,1) CE(s,2,3) CE(s,4,5) CE(s,6,7) \
    CE(s,0,2) CE(s,1,3) CE(s,4,6) CE(s,5,7) \
    CE(s,1,2) CE(s,5,6) \
    CE(s,0,4) CE(s,1,5) CE(s,2,6) CE(s,3,7) \
    CE(s,2,4) CE(s,3,5) \
    CE(s,1,2) CE(s,3,4) CE(s,5,6)

// xor-lane exchange: ds_swizzle for off<=16; shfl for 32 (R8-proven idioms)
#define SWZ(v, IMM) __int_as_float(__builtin_amdgcn_ds_swizzle(__float_as_int(v), IMM))

#define BFLY_LEVEL(XCHG) { \
    float q[4][8]; \
    _Pragma("unroll") \
    for (int tt = 0; tt < 4; ++tt) { \
        _Pragma("unroll") \
        for (int i = 0; i < 8; ++i) { float _x = s[tt][i]; q[tt][i] = XCHG(_x); } \
    } \
    _Pragma("unroll") \
    for (int tt = 0; tt < 4; ++tt) { \
        float c[8]; \
        c[0] = fmaxf(s[tt][0], q[tt][7]); c[1] = fmaxf(s[tt][1], q[tt][6]); \
        c[2] = fmaxf(s[tt][2], q[tt][5]); c[3] = fmaxf(s[tt][3], q[tt][4]); \
        c[4] = fmaxf(s[tt][4], q[tt][3]); c[5] = fmaxf(s[tt][5], q[tt][2]); \
        c[6] = fmaxf(s[tt][6], q[tt][1]); c[7] = fmaxf(s[tt][7], q[tt][0]); \
        CE(c,0,4) CE(c,1,5) CE(c,2,6) CE(c,3,7) \
        CE(c,0,2) CE(c,1,3) CE(c,4,6) CE(c,5,7) \
        CE(c,0,1) CE(c,2,3) CE(c,4,5) CE(c,6,7) \
        _Pragma("unroll") \
        for (int i = 0; i < 8; ++i) s[tt][i] = c[i]; \
    } }

#define X1(v)  SWZ(v, 0x041F)
#define X2(v)  SWZ(v, 0x081F)
#define X4_(v) SWZ(v, 0x101F)
#define X8(v)  SWZ(v, 0x201F)
#define X16(v) SWZ(v, 0x401F)
#define X32(v) __shfl_xor(v, 32, 64)

// ---------------- K3: logits + softmax + top8 + dense write (R8 form)
// (256,3): VGPR was 84 at (256,2) -> fits the ~85 cap, +50% TLP (8->12 waves).
__global__ __launch_bounds__(256, 3) void k_router(const float* __restrict__ P,
                                                   const float* __restrict__ embT,
                                                   float* __restrict__ out, int SK) {
    __shared__ float hsh[32][DSPACE];   // 8 KB, wave-disjoint token rows
    const int head = blockIdx.y;
    const int t0   = blockIdx.x * 32;
    const int tid  = threadIdx.x;
    const int wid  = tid >> 6;
    const int lane = tid & 63;
    const int so = (head == 2) ? 512 : (head == 3 || head == 4) ? 1024
                 : (head == 5) ? 1536 : 0;

    // wave stages its own 8 tokens (no barrier; DS FIFO per wave)
    {
        int t  = (wid << 3) + (lane >> 3);
        int d0 = (lane & 7) << 3;
        size_t off = (size_t)(t0 + t) * PROJN + head * DSPACE + d0;
        float4 v0 = *(const float4*)&P[off];
        float4 v1 = *(const float4*)&P[off + 4];
        for (int ks = 1; ks < SK; ++ks) {
            size_t o2 = (size_t)ks * NTOK * PROJN + off;
            float4 u0 = *(const float4*)&P[o2];
            float4 u1 = *(const float4*)&P[o2 + 4];
            v0.x += u0.x; v0.y += u0.y; v0.z += u0.z; v0.w += u0.w;
            v1.x += u1.x; v1.y += u1.y; v1.z += u1.z; v1.w += u1.w;
        }
        *(float4*)&hsh[t][d0]     = v0;
        *(float4*)&hsh[t][d0 + 4] = v1;
    }

    // logits: wave handles 8 tokens; lane owns n = 8*lane + j (4 f32x2 pairs)
    f32x2 acc2[8][4];
#pragma unroll
    for (int t = 0; t < 8; ++t)
#pragma unroll
        for (int p = 0; p < 4; ++p) acc2[t][p] = (f32x2){0.f, 0.f};

    const float* ebase = &embT[so + (lane << 3)];
    for (int d4 = 0; d4 < DSPACE; d4 += 4) {
        f32x2 hp[8][2];
#pragma unroll
        for (int t = 0; t < 8; ++t) {
            hp[t][0] = *(const f32x2*)&hsh[(wid << 3) + t][d4];
            hp[t][1] = *(const f32x2*)&hsh[(wid << 3) + t][d4 + 2];
        }
#pragma unroll
        for (int dp = 0; dp < 2; ++dp) {
            const float* er0 = ebase + (size_t)(d4 + 2 * dp) * 2048;
            const float* er1 = er0 + 2048;
            f32x2 ea[4], eb[4];
#pragma unroll
            for (int p = 0; p < 4; ++p) {
                ea[p] = *(const f32x2*)&er0[2 * p];
                eb[p] = *(const f32x2*)&er1[2 * p];
            }
#pragma unroll
            for (int t = 0; t < 8; ++t) {
#pragma unroll
                for (int p = 0; p < 4; ++p) {
                    PK_LO(acc2[t][p], ea[p], hp[t][dp]);   // d even: hv .lo
                    PK_HI(acc2[t][p], eb[p], hp[t][dp]);   // d odd : hv .hi
                }
            }
        }
    }

    const size_t obase = ((size_t)head * NTOK + t0 + (wid << 3)) * NPOOL;

#pragma unroll
    for (int g = 0; g < 2; ++g) {
        float l[4][8], s[4][8];
#pragma unroll
        for (int tt = 0; tt < 4; ++tt)
#pragma unroll
            for (int j = 0; j < 8; ++j) {
                f32x2 v = acc2[4 * g + tt][j >> 1];
                l[tt][j] = (j & 1) ? v.y : v.x;
                s[tt][j] = l[tt][j];
            }

        SORT8(s[0]) SORT8(s[1]) SORT8(s[2]) SORT8(s[3])

        BFLY_LEVEL(X1)
        BFLY_LEVEL(X2)
        BFLY_LEVEL(X4_)
        BFLY_LEVEL(X8)
        BFLY_LEVEL(X16)
        BFLY_LEVEL(X32)

        unsigned gtm[4], eqm[4]; int own[4], inc[4];
#pragma unroll
        for (int tt = 0; tt < 4; ++tt) {
            const float T = s[tt][7];
            unsigned g_ = 0, e_ = 0; int cg = 0, ce = 0;
#pragma unroll
            for (int j = 0; j < 8; ++j) {
                if (l[tt][j] > T)       { g_ |= 1u << j; ++cg; }
                else if (l[tt][j] == T) { e_ |= 1u << j; ++ce; }
            }
            gtm[tt] = g_; eqm[tt] = e_;
            own[tt] = (ce << 8) | cg;
            inc[tt] = own[tt];
        }
#pragma unroll
        for (int off = 1; off < 64; off <<= 1) {
            int v0 = __shfl_up(inc[0], off, 64);
            int v1 = __shfl_up(inc[1], off, 64);
            int v2 = __shfl_up(inc[2], off, 64);
            int v3 = __shfl_up(inc[3], off, 64);
            if (lane >= off) { inc[0] += v0; inc[1] += v1; inc[2] += v2; inc[3] += v3; }
        }

#pragma unroll
        for (int tt = 0; tt < 4; ++tt) {
            const float T = s[tt][7];
            const float m = s[tt][0];
            int tot  = __shfl(inc[tt], 63, 64);
            int need = 8 - (tot & 0xff);
            int eqpre = (inc[tt] - own[tt]) >> 8;
            unsigned sel = gtm[tt];
#pragma unroll
            for (int j = 0; j < 8; ++j) {
                if ((eqm[tt] >> j) & 1u) { if (eqpre < need) sel |= 1u << j; ++eqpre; }
            }

            float s8 = 0.f;
#pragma unroll
            for (int i = 0; i < 8; ++i) s8 += __expf(s[tt][i] - m);
            float invd = 1.0f / s8;     // s8-only denominator (<=5e-6 rel)

            float o[8];
#pragma unroll
            for (int j = 0; j < 8; ++j)
                o[j] = ((sel >> j) & 1u) ? __expf(l[tt][j] - m) * invd : 0.0f;
            float4* dst = (float4*)&out[obase + (size_t)(4 * g + tt) * NPOOL + (lane << 3)];
            dst[0] = *(float4*)&o[0];
            dst[1] = *(float4*)&o[4];
        }
    }
}

extern "C" void kernel_launch(void* const* d_in, const int* in_sizes, int n_in,
                              void* d_out, int out_size, void* d_ws, size_t ws_size,
                              hipStream_t stream) {
    const float* x   = (const float*)d_in[0];
    const float* W   = (const float*)d_in[1];
    const float* b   = (const float*)d_in[2];
    const float* emb = (const float*)d_in[3];
    float* out  = (float*)d_out;
    float* embT = (float*)d_ws;                       // 64*2048 f32 = 512 KB
    float* proj = embT + 64 * 2048;                   // SK slabs of 8192*384 f32

    size_t base = (size_t)64 * 2048 * 4;
    size_t slab = (size_t)NTOK * PROJN * 4;           // 12.58 MB
    int SK = (ws_size >= base + 4 * slab) ? 4
           : (ws_size >= base + 2 * slab) ? 2 : 1;
    int KS = DMODEL / SK;

    k_norm_emb<<<dim3(512), dim3(256), 0, stream>>>(emb, embT);
    dim3 g2(NTOK / 128, PROJN / 64, SK);
    k_proj<<<g2, dim3(128), 0, stream>>>(x, W, b, proj, KS);
    dim3 g3(NTOK / 32, NHEADS);
    k_router<<<g3, dim3(256), 0, stream>>>(proj, embT, out, SK);
}

// Round 16
// 175.257 us; speedup vs baseline: 1.1828x; 1.1828x over previous
//
#include <hip/hip_runtime.h>
#include <math.h>

#define NB 4
#define NS 2048
#define DMODEL 1024
#define DSPACE 64
#define NPOOL 512
#define NHEADS 6
#define NTOK (NB * NS)            // 8192
#define PROJN (NHEADS * DSPACE)   // 384
#define EPSF 1e-8f

typedef float f32x2 __attribute__((ext_vector_type(2)));

// packed f32 FMA: both halves multiply by S1.lo / S1.hi (broadcast via op_sel)
#define PK_LO(ACC, A2, B2) \
    asm("v_pk_fma_f32 %0, %1, %2, %0 op_sel:[0,0,0] op_sel_hi:[1,0,1]" \
        : "+v"(ACC) : "v"(A2), "v"(B2))
#define PK_HI(ACC, A2, B2) \
    asm("v_pk_fma_f32 %0, %1, %2, %0 op_sel:[0,1,0] op_sel_hi:[1,1,1]" \
        : "+v"(ACC) : "v"(A2), "v"(B2))

// ---------------- K1: normalize neuron_emb rows [0,2048) -> embT[64][2048]
__global__ __launch_bounds__(256) void k_norm_emb(const float* __restrict__ emb,
                                                  float* __restrict__ embT) {
    int row  = blockIdx.x * 4 + (threadIdx.x >> 6);
    int lane = threadIdx.x & 63;
    float v  = emb[row * DSPACE + lane];
    float ss = v * v;
#pragma unroll
    for (int off = 32; off >= 1; off >>= 1) ss += __shfl_xor(ss, off, 64);
    float nrm = sqrtf(ss) + EPSF;
    embT[lane * 2048 + row] = v / nrm;
}

// ---------------- K2: proj = X @ W + b, split-K partials (R8-exact, ~71us)
// Five structural alternatives (split-K spill, barrier-free, 16x8 tile,
// SMEM-W, all-VMEM) all regressed; this LDS-dbuf form is the proven optimum.
__global__ __launch_bounds__(128, 4) void k_proj(const float* __restrict__ X,
                                                 const float* __restrict__ W,
                                                 const float* __restrict__ bias,
                                                 float* __restrict__ P, int KS) {
    __shared__ float Xt[2][16 * 128];   // 16 KB
    __shared__ float Wt[2][16 * 64];    // 8 KB
    const int tid = threadIdx.x;
    const int bm  = blockIdx.x * 128;
    const int bn  = blockIdx.y * 64;
    const int z   = blockIdx.z;
    float* Pp = P + (size_t)z * NTOK * PROJN;

    const int r0  = (tid >> 3) << 2;   // 0..60
    const int c0  = (tid & 7) << 2;    // 0..28
    const int lwr = tid >> 3;          // 0..15
    const int lwc = (tid & 7) << 3;    // 0..56

    const float* Xrow = X + (size_t)(bm + tid) * DMODEL;

    f32x2 acc2[4][8];
#pragma unroll
    for (int p = 0; p < 4; ++p)
#pragma unroll
        for (int j = 0; j < 8; ++j) acc2[p][j] = (f32x2){0.f, 0.f};

    const int nsteps = KS >> 4;
    int k0 = z * KS;
    float4 xr0 = *(const float4*)&Xrow[k0 + 0];
    float4 xr1 = *(const float4*)&Xrow[k0 + 4];
    float4 xr2 = *(const float4*)&Xrow[k0 + 8];
    float4 xr3 = *(const float4*)&Xrow[k0 + 12];
    float4 wg0 = *(const float4*)&W[(size_t)(k0 + lwr) * PROJN + bn + lwc];
    float4 wg1 = *(const float4*)&W[(size_t)(k0 + lwr) * PROJN + bn + lwc + 4];

    {   // prologue: stage tile 0 into buffer 0
        float* xb = Xt[0]; float* wb = Wt[0];
        xb[ 0*128+tid]=xr0.x; xb[ 1*128+tid]=xr0.y; xb[ 2*128+tid]=xr0.z; xb[ 3*128+tid]=xr0.w;
        xb[ 4*128+tid]=xr1.x; xb[ 5*128+tid]=xr1.y; xb[ 6*128+tid]=xr1.z; xb[ 7*128+tid]=xr1.w;
        xb[ 8*128+tid]=xr2.x; xb[ 9*128+tid]=xr2.y; xb[10*128+tid]=xr2.z; xb[11*128+tid]=xr2.w;
        xb[12*128+tid]=xr3.x; xb[13*128+tid]=xr3.y; xb[14*128+tid]=xr3.z; xb[15*128+tid]=xr3.w;
        *(float4*)&wb[lwr * 64 + lwc]     = wg0;
        *(float4*)&wb[lwr * 64 + lwc + 4] = wg1;
    }

    for (int s = 0; s < nsteps; ++s) {
        if (s + 1 < nsteps) {
            int k1 = k0 + 16;
            xr0 = *(const float4*)&Xrow[k1 + 0];
            xr1 = *(const float4*)&Xrow[k1 + 4];
            xr2 = *(const float4*)&Xrow[k1 + 8];
            xr3 = *(const float4*)&Xrow[k1 + 12];
            wg0 = *(const float4*)&W[(size_t)(k1 + lwr) * PROJN + bn + lwc];
            wg1 = *(const float4*)&W[(size_t)(k1 + lwr) * PROJN + bn + lwc + 4];
        }
        __syncthreads();
        if (s + 1 < nsteps) {
            float* xb = Xt[(s + 1) & 1]; float* wb = Wt[(s + 1) & 1];
            xb[ 0*128+tid]=xr0.x; xb[ 1*128+tid]=xr0.y; xb[ 2*128+tid]=xr0.z; xb[ 3*128+tid]=xr0.w;
            xb[ 4*128+tid]=xr1.x; xb[ 5*128+tid]=xr1.y; xb[ 6*128+tid]=xr1.z; xb[ 7*128+tid]=xr1.w;
            xb[ 8*128+tid]=xr2.x; xb[ 9*128+tid]=xr2.y; xb[10*128+tid]=xr2.z; xb[11*128+tid]=xr2.w;
            xb[12*128+tid]=xr3.x; xb[13*128+tid]=xr3.y; xb[14*128+tid]=xr3.z; xb[15*128+tid]=xr3.w;
            *(float4*)&wb[lwr * 64 + lwc]     = wg0;
            *(float4*)&wb[lwr * 64 + lwc + 4] = wg1;
        }
        const float* xc = Xt[s & 1];
        const float* wc = Wt[s & 1];
#pragma unroll
        for (int kk = 0; kk < 16; ++kk) {
            float4 a0 = *(const float4*)&xc[kk * 128 + r0];
            float4 a1 = *(const float4*)&xc[kk * 128 + r0 + 64];
            float4 b0 = *(const float4*)&wc[kk * 64 + c0];
            float4 b1 = *(const float4*)&wc[kk * 64 + c0 + 32];
            f32x2 ap0 = (f32x2){a0.x, a0.y};
            f32x2 ap1 = (f32x2){a0.z, a0.w};
            f32x2 ap2 = (f32x2){a1.x, a1.y};
            f32x2 ap3 = (f32x2){a1.z, a1.w};
            f32x2 bq0 = (f32x2){b0.x, b0.y};
            f32x2 bq1 = (f32x2){b0.z, b0.w};
            f32x2 bq2 = (f32x2){b1.x, b1.y};
            f32x2 bq3 = (f32x2){b1.z, b1.w};
#pragma unroll
            for (int p = 0; p < 4; ++p) {
                f32x2 ap = (p == 0) ? ap0 : (p == 1) ? ap1 : (p == 2) ? ap2 : ap3;
                PK_LO(acc2[p][0], ap, bq0); PK_HI(acc2[p][1], ap, bq0);
                PK_LO(acc2[p][2], ap, bq1); PK_HI(acc2[p][3], ap, bq1);
                PK_LO(acc2[p][4], ap, bq2); PK_HI(acc2[p][5], ap, bq2);
                PK_LO(acc2[p][6], ap, bq3); PK_HI(acc2[p][7], ap, bq3);
            }
        }
        k0 += 16;
    }

#pragma unroll
    for (int i = 0; i < 8; ++i) {
        int row = bm + r0 + ((i < 4) ? i : 60 + i);
        float o0[4], o1[4];
#pragma unroll
        for (int j = 0; j < 4; ++j) {
            f32x2 v0 = acc2[i >> 1][j];
            f32x2 v1 = acc2[i >> 1][j + 4];
            o0[j] = (i & 1) ? v0.y : v0.x;
            o1[j] = (i & 1) ? v1.y : v1.x;
        }
        if (z == 0) {
#pragma unroll
            for (int j = 0; j < 4; ++j) {
                o0[j] += bias[bn + c0 + j];
                o1[j] += bias[bn + c0 + 32 + j];
            }
        }
        *(float4*)&Pp[(size_t)row * PROJN + bn + c0]      = *(float4*)&o0[0];
        *(float4*)&Pp[(size_t)row * PROJN + bn + c0 + 32] = *(float4*)&o1[0];
    }
}

// compare-exchange keeping larger value at index a (descending order)
#define CE(arr, a, b) { float _hi = fmaxf(arr[a], arr[b]); arr[b] = fminf(arr[a], arr[b]); arr[a] = _hi; }

#define SORT8(s) \
    CE(s,0,1) CE(s,2,3) CE(s,4,5) CE(s,6,7) \
    CE(s,0,2) CE(s,1,3) CE(s,4,6) CE(s,5,7) \
    CE(s,1,2) CE(s,5,6) \
    CE(s,0,4) CE(s,1,5) CE(s,2,6) CE(s,3,7) \
    CE(s,2,4) CE(s,3,5) \
    CE(s,1,2) CE(s,3,4) CE(s,5,6)

// xor-lane exchange: ds_swizzle for off<=16; shfl for 32 (R8-proven idioms)
#define SWZ(v, IMM) __int_as_float(__builtin_amdgcn_ds_swizzle(__float_as_int(v), IMM))

#define BFLY_LEVEL(XCHG) { \
    float q[4][8]; \
    _Pragma("unroll") \
    for (int tt = 0; tt < 4; ++tt) { \
        _Pragma("unroll") \
        for (int i = 0; i < 8; ++i) { float _x = s[tt][i]; q[tt][i] = XCHG(_x); } \
    } \
    _Pragma("unroll") \
    for (int tt = 0; tt < 4; ++tt) { \
        float c[8]; \
        c[0] = fmaxf(s[tt][0], q[tt][7]); c[1] = fmaxf(s[tt][1], q[tt][6]); \
        c[2] = fmaxf(s[tt][2], q[tt][5]); c[3] = fmaxf(s[tt][3], q[tt][4]); \
        c[4] = fmaxf(s[tt][4], q[tt][3]); c[5] = fmaxf(s[tt][5], q[tt][2]); \
        c[6] = fmaxf(s[tt][6], q[tt][1]); c[7] = fmaxf(s[tt][7], q[tt][0]); \
        CE(c,0,4) CE(c,1,5) CE(c,2,6) CE(c,3,7) \
        CE(c,0,2) CE(c,1,3) CE(c,4,6) CE(c,5,7) \
        CE(c,0,1) CE(c,2,3) CE(c,4,5) CE(c,6,7) \
        _Pragma("unroll") \
        for (int i = 0; i < 8; ++i) s[tt][i] = c[i]; \
    } }

#define X1(v)  SWZ(v, 0x041F)
#define X2(v)  SWZ(v, 0x081F)
#define X4_(v) SWZ(v, 0x101F)
#define X8(v)  SWZ(v, 0x201F)
#define X16(v) SWZ(v, 0x401F)
#define X32(v) __shfl_xor(v, 32, 64)

// ---------------- K3: logits + softmax + top8 + dense write
// (256,3): 12 waves/SIMD-group vs 8 — measured ~58us in R15 (was 102 at (256,2)).
// Per-wave stall (~85%) was the binding constraint; +50% TLP fills it.
__global__ __launch_bounds__(256, 3) void k_router(const float* __restrict__ P,
                                                   const float* __restrict__ embT,
                                                   float* __restrict__ out, int SK) {
    __shared__ float hsh[32][DSPACE];   // 8 KB, wave-disjoint token rows
    const int head = blockIdx.y;
    const int t0   = blockIdx.x * 32;
    const int tid  = threadIdx.x;
    const int wid  = tid >> 6;
    const int lane = tid & 63;
    const int so = (head == 2) ? 512 : (head == 3 || head == 4) ? 1024
                 : (head == 5) ? 1536 : 0;

    // wave stages its own 8 tokens (no barrier; DS FIFO per wave)
    {
        int t  = (wid << 3) + (lane >> 3);
        int d0 = (lane & 7) << 3;
        size_t off = (size_t)(t0 + t) * PROJN + head * DSPACE + d0;
        float4 v0 = *(const float4*)&P[off];
        float4 v1 = *(const float4*)&P[off + 4];
        for (int ks = 1; ks < SK; ++ks) {
            size_t o2 = (size_t)ks * NTOK * PROJN + off;
            float4 u0 = *(const float4*)&P[o2];
            float4 u1 = *(const float4*)&P[o2 + 4];
            v0.x += u0.x; v0.y += u0.y; v0.z += u0.z; v0.w += u0.w;
            v1.x += u1.x; v1.y += u1.y; v1.z += u1.z; v1.w += u1.w;
        }
        *(float4*)&hsh[t][d0]     = v0;
        *(float4*)&hsh[t][d0 + 4] = v1;
    }

    // logits: wave handles 8 tokens; lane owns n = 8*lane + j (4 f32x2 pairs)
    f32x2 acc2[8][4];
#pragma unroll
    for (int t = 0; t < 8; ++t)
#pragma unroll
        for (int p = 0; p < 4; ++p) acc2[t][p] = (f32x2){0.f, 0.f};

    const float* ebase = &embT[so + (lane << 3)];
    for (int d4 = 0; d4 < DSPACE; d4 += 4) {
        f32x2 hp[8][2];
#pragma unroll
        for (int t = 0; t < 8; ++t) {
            hp[t][0] = *(const f32x2*)&hsh[(wid << 3) + t][d4];
            hp[t][1] = *(const f32x2*)&hsh[(wid << 3) + t][d4 + 2];
        }
#pragma unroll
        for (int dp = 0; dp < 2; ++dp) {
            const float* er0 = ebase + (size_t)(d4 + 2 * dp) * 2048;
            const float* er1 = er0 + 2048;
            f32x2 ea[4], eb[4];
#pragma unroll
            for (int p = 0; p < 4; ++p) {
                ea[p] = *(const f32x2*)&er0[2 * p];
                eb[p] = *(const f32x2*)&er1[2 * p];
            }
#pragma unroll
            for (int t = 0; t < 8; ++t) {
#pragma unroll
                for (int p = 0; p < 4; ++p) {
                    PK_LO(acc2[t][p], ea[p], hp[t][dp]);   // d even: hv .lo
                    PK_HI(acc2[t][p], eb[p], hp[t][dp]);   // d odd : hv .hi
                }
            }
        }
    }

    const size_t obase = ((size_t)head * NTOK + t0 + (wid << 3)) * NPOOL;

#pragma unroll
    for (int g = 0; g < 2; ++g) {
        float l[4][8], s[4][8];
#pragma unroll
        for (int tt = 0; tt < 4; ++tt)
#pragma unroll
            for (int j = 0; j < 8; ++j) {
                f32x2 v = acc2[4 * g + tt][j >> 1];
                l[tt][j] = (j & 1) ? v.y : v.x;
                s[tt][j] = l[tt][j];
            }

        SORT8(s[0]) SORT8(s[1]) SORT8(s[2]) SORT8(s[3])

        BFLY_LEVEL(X1)
        BFLY_LEVEL(X2)
        BFLY_LEVEL(X4_)
        BFLY_LEVEL(X8)
        BFLY_LEVEL(X16)
        BFLY_LEVEL(X32)

        unsigned gtm[4], eqm[4]; int own[4], inc[4];
#pragma unroll
        for (int tt = 0; tt < 4; ++tt) {
            const float T = s[tt][7];
            unsigned g_ = 0, e_ = 0; int cg = 0, ce = 0;
#pragma unroll
            for (int j = 0; j < 8; ++j) {
                if (l[tt][j] > T)       { g_ |= 1u << j; ++cg; }
                else if (l[tt][j] == T) { e_ |= 1u << j; ++ce; }
            }
            gtm[tt] = g_; eqm[tt] = e_;
            own[tt] = (ce << 8) | cg;
            inc[tt] = own[tt];
        }
#pragma unroll
        for (int off = 1; off < 64; off <<= 1) {
            int v0 = __shfl_up(inc[0], off, 64);
            int v1 = __shfl_up(inc[1], off, 64);
            int v2 = __shfl_up(inc[2], off, 64);
            int v3 = __shfl_up(inc[3], off, 64);
            if (lane >= off) { inc[0] += v0; inc[1] += v1; inc[2] += v2; inc[3] += v3; }
        }

#pragma unroll
        for (int tt = 0; tt < 4; ++tt) {
            const float T = s[tt][7];
            const float m = s[tt][0];
            int tot  = __shfl(inc[tt], 63, 64);
            int need = 8 - (tot & 0xff);
            int eqpre = (inc[tt] - own[tt]) >> 8;
            unsigned sel = gtm[tt];
#pragma unroll
            for (int j = 0; j < 8; ++j) {
                if ((eqm[tt] >> j) & 1u) { if (eqpre < need) sel |= 1u << j; ++eqpre; }
            }

            float s8 = 0.f;
#pragma unroll
            for (int i = 0; i < 8; ++i) s8 += __expf(s[tt][i] - m);
            float invd = 1.0f / s8;     // s8-only denominator (<=5e-6 rel)

            float o[8];
#pragma unroll
            for (int j = 0; j < 8; ++j)
                o[j] = ((sel >> j) & 1u) ? __expf(l[tt][j] - m) * invd : 0.0f;
            float4* dst = (float4*)&out[obase + (size_t)(4 * g + tt) * NPOOL + (lane << 3)];
            dst[0] = *(float4*)&o[0];
            dst[1] = *(float4*)&o[4];
        }
    }
}

extern "C" void kernel_launch(void* const* d_in, const int* in_sizes, int n_in,
                              void* d_out, int out_size, void* d_ws, size_t ws_size,
                              hipStream_t stream) {
    const float* x   = (const float*)d_in[0];
    const float* W   = (const float*)d_in[1];
    const float* b   = (const float*)d_in[2];
    const float* emb = (const float*)d_in[3];
    float* out  = (float*)d_out;
    float* embT = (float*)d_ws;                       // 64*2048 f32 = 512 KB
    float* proj = embT + 64 * 2048;                   // SK slabs of 8192*384 f32

    size_t base = (size_t)64 * 2048 * 4;
    size_t slab = (size_t)NTOK * PROJN * 4;           // 12.58 MB
    int SK = (ws_size >= base + 4 * slab) ? 4
           : (ws_size >= base + 2 * slab) ? 2 : 1;
    int KS = DMODEL / SK;

    k_norm_emb<<<dim3(512), dim3(256), 0, stream>>>(emb, embT);
    dim3 g2(NTOK / 128, PROJN / 64, SK);
    k_proj<<<g2, dim3(128), 0, stream>>>(x, W, b, proj, KS);
    dim3 g3(NTOK / 32, NHEADS);
    k_router<<<g3, dim3(256), 0, stream>>>(proj, embT, out, SK);
}